// Round 14
// baseline (298.167 us; speedup 1.0000x reference)
//
#include <hip/hip_runtime.h>
#include <hip/hip_bf16.h>

#define TA_B 2
#define TA_H 16
#define TA_S 2048
#define TA_D 64
#define KTILE 64
#define QB 128
#define BLOCK 512
#define NKT (TA_S / KTILE)
#define NSPLIT 4
#define KT_PER (NKT / NSPLIT)

typedef __attribute__((ext_vector_type(4))) float f32x4;
typedef __attribute__((ext_vector_type(8))) short bf16x8;
typedef __attribute__((ext_vector_type(8))) unsigned short u16x8;
typedef __attribute__((ext_vector_type(4))) unsigned short u16x4;
typedef __attribute__((ext_vector_type(2))) unsigned int u32x2;

union BF8 { u16x8 u; bf16x8 s; };

__device__ __forceinline__ unsigned short f2bf(float f) {
    union { float f; unsigned int i; } v; v.f = f;
    unsigned int x = v.i;
    unsigned int r = x + 0x7FFFu + ((x >> 16) & 1u);
    return (unsigned short)(r >> 16);
}
__device__ __forceinline__ float bf2f(unsigned short u) {
    union { unsigned int i; float f; } v; v.i = ((unsigned int)u) << 16; return v.f;
}

__device__ __forceinline__ void barrier_lds() {
    asm volatile("s_waitcnt lgkmcnt(0)" ::: "memory");
    __builtin_amdgcn_sched_barrier(0);
    __builtin_amdgcn_s_barrier();
    __builtin_amdgcn_sched_barrier(0);
}

// ---- mask bit-pack: 33.6 MB int32 -> 1 MB bits, via wave ballot ----
__global__ __launch_bounds__(256) void pack_mask(const int* __restrict__ M,
                                                 unsigned long long* __restrict__ Mp) {
    const int nw = TA_B * TA_S * NKT;
    const int wavesTotal = (gridDim.x * blockDim.x) >> 6;
    const int wid  = (blockIdx.x * blockDim.x + threadIdx.x) >> 6;
    const int lane = threadIdx.x & 63;
    for (int w = wid; w < nw; w += wavesTotal) {
        int mv = M[(long)w * 64 + lane];
        unsigned long long bits = __ballot(mv != 0);
        if (lane == 0) Mp[w] = bits;
    }
}

// ---- Pass A, split-K: partial l over KT_PER tiles -> wsL[q][split] ----
__global__ __launch_bounds__(BLOCK, 4) void ta_passA(
    const float* __restrict__ Qg,
    const float* __restrict__ Kg,
    const float* __restrict__ Tg,
    const unsigned long long* __restrict__ Mp,
    float* __restrict__ wsL)
{
    __shared__ unsigned short sKp[2][KTILE][72];   // dbuf bf16(K+T)

    const int tid  = threadIdx.x;
    const int wave = tid >> 6;
    const int lane = tid & 63;
    const int c    = lane & 15;
    const int g    = lane >> 4;
    const int row0 = tid >> 3;
    const int cg   = (tid & 7) * 8;

    // Bijective XCD swizzle over 2048 blocks; consecutive wid share (b,h,split).
    const int did = blockIdx.x + 64 * (blockIdx.y + 16 * blockIdx.z);
    const int wid = (did & 7) * 256 + (did >> 3);
    const int q0    = (wid & 15) * QB;
    const int split = (wid >> 4) & 3;
    const int h     = (wid >> 6) & 15;
    const int b     = wid >> 10;

    const long bh    = (long)b * TA_H + h;
    const long xBase = bh * (long)TA_S * TA_D;
    const int  wq0   = wave * 16;
    const int  myq   = q0 + wq0 + c;
    const int  kt0   = split * KT_PER;

    bf16x8 qf0, qf1;
    {
        const float* qp = Qg + xBase + (long)myq * TA_D + g * 8;
        f32x4 a0 = *(const f32x4*)(qp);
        f32x4 a1 = *(const f32x4*)(qp + 4);
        f32x4 b0 = *(const f32x4*)(qp + 32);
        f32x4 b1 = *(const f32x4*)(qp + 36);
        BF8 u0, u1;
#pragma unroll
        for (int i = 0; i < 4; ++i) {
            u0.u[i]     = f2bf(a0[i] * 0.125f);
            u0.u[i + 4] = f2bf(a1[i] * 0.125f);
            u1.u[i]     = f2bf(b0[i] * 0.125f);
            u1.u[i + 4] = f2bf(b1[i] * 0.125f);
        }
        qf0 = u0.s; qf1 = u1.s;
    }

    f32x4 kA0, kA1, tA0, tA1;
    auto loadKT = [&](int kt) {
        const long o0 = xBase + (long)(kt * KTILE + row0) * TA_D + cg;
        kA0 = *(const f32x4*)(Kg + o0); kA1 = *(const f32x4*)(Kg + o0 + 4);
        tA0 = *(const f32x4*)(Tg + o0); tA1 = *(const f32x4*)(Tg + o0 + 4);
    };
    auto storeKp = [&](int p) {
        u16x8 r0;
#pragma unroll
        for (int i = 0; i < 4; ++i) {
            r0[i]     = f2bf(kA0[i] + tA0[i]);
            r0[i + 4] = f2bf(kA1[i] + tA1[i]);
        }
        *(u16x8*)&sKp[p][row0][cg] = r0;
    };

    float lpart = 0.0f;
    loadKT(kt0);
    for (int i = 0; i < KT_PER; ++i) {
        const int kt = kt0 + i;
        const int p  = i & 1;
        storeKp(p);
        loadKT(i + 1 < KT_PER ? kt + 1 : kt0);
        barrier_lds();

        f32x4 acc[4];
#pragma unroll
        for (int ct = 0; ct < 4; ++ct)
#pragma unroll
            for (int j = 0; j < 4; ++j) acc[ct][j] = 0.0f;

        __builtin_amdgcn_s_setprio(1);
#pragma unroll
        for (int kk = 0; kk < 2; ++kk) {
            bf16x8 qa = kk ? qf1 : qf0;
#pragma unroll
            for (int ct = 0; ct < 4; ++ct) {
                BF8 bf; bf.u = *(const u16x8*)&sKp[p][ct * 16 + c][kk * 32 + g * 8];
                acc[ct] = __builtin_amdgcn_mfma_f32_16x16x32_bf16(bf.s, qa, acc[ct], 0, 0, 0);
            }
        }
        __builtin_amdgcn_s_setprio(0);

        const unsigned long long w = Mp[((long)b * TA_S + myq) * NKT + kt];
#pragma unroll
        for (int ct = 0; ct < 4; ++ct) {
            const unsigned nib = (unsigned)(w >> (ct * 16 + g * 4)) & 0xFu;
#pragma unroll
            for (int r = 0; r < 4; ++r)
                lpart += ((nib >> r) & 1u) ? __expf(acc[ct][r]) : 0.0f;
        }
        // no trailing barrier: next tile writes buffer p^1
    }

    float l = lpart;
    l += __shfl_xor(l, 16);
    l += __shfl_xor(l, 32);
    if (g == 0)
        wsL[((long)bh * TA_S + myq) * NSPLIT + split] = l;
}

// ---- Pass B: reads summed l, recomputes S^T, writes normalized P + O ----
__global__ __launch_bounds__(BLOCK, 4) void ta_passB(
    const float* __restrict__ Qg,
    const float* __restrict__ Kg,
    const float* __restrict__ Vg,
    const float* __restrict__ Tg,
    const unsigned long long* __restrict__ Mp,
    const float* __restrict__ wsL,
    float* __restrict__ Og,
    float* __restrict__ Pg)
{
    __shared__ unsigned short sKp[2][KTILE][72];
    __shared__ unsigned short sVt[2][TA_D][72];
    __shared__ unsigned short sP[QB][72];

    const int tid  = threadIdx.x;
    const int wave = tid >> 6;
    const int lane = tid & 63;
    const int c    = lane & 15;
    const int g    = lane >> 4;
    const int row0 = tid >> 3;
    const int cg   = (tid & 7) * 8;

    const int did = blockIdx.x + 16 * (blockIdx.y + 16 * blockIdx.z);
    const int wid = (did & 7) * 64 + (did >> 3);
    const int q0  = (wid & 15) * QB;
    const int h   = (wid >> 4) & 15;
    const int b   = wid >> 8;

    const long bh    = (long)b * TA_H + h;
    const long xBase = bh * (long)TA_S * TA_D;
    const long pBase = bh * (long)TA_S * TA_S;
    const int  wq0   = wave * 16;
    const int  myq   = q0 + wq0 + c;

    bf16x8 qf0, qf1;
    {
        const float* qp = Qg + xBase + (long)myq * TA_D + g * 8;
        f32x4 a0 = *(const f32x4*)(qp);
        f32x4 a1 = *(const f32x4*)(qp + 4);
        f32x4 b0 = *(const f32x4*)(qp + 32);
        f32x4 b1 = *(const f32x4*)(qp + 36);
        BF8 u0, u1;
#pragma unroll
        for (int i = 0; i < 4; ++i) {
            u0.u[i]     = f2bf(a0[i] * 0.125f);
            u0.u[i + 4] = f2bf(a1[i] * 0.125f);
            u1.u[i]     = f2bf(b0[i] * 0.125f);
            u1.u[i + 4] = f2bf(b1[i] * 0.125f);
        }
        qf0 = u0.s; qf1 = u1.s;
    }

    // l = sum of 4 split partials (one f32x4 load per lane)
    float invl;
    {
        f32x4 lp = *(const f32x4*)&wsL[((long)bh * TA_S + myq) * NSPLIT];
        float l = lp[0] + lp[1] + lp[2] + lp[3];
        invl = (l > 0.0f) ? (1.0f / l) : 0.0f;
    }

    f32x4 kA0, kA1, tA0, tA1, vA0, vA1;
    auto loadKT = [&](int kt) {
        const long o0 = xBase + (long)(kt * KTILE + row0) * TA_D + cg;
        kA0 = *(const f32x4*)(Kg + o0); kA1 = *(const f32x4*)(Kg + o0 + 4);
        tA0 = *(const f32x4*)(Tg + o0); tA1 = *(const f32x4*)(Tg + o0 + 4);
    };
    auto loadV = [&](int kt) {
        const long o0 = xBase + (long)(kt * KTILE + row0) * TA_D + cg;
        vA0 = *(const f32x4*)(Vg + o0); vA1 = *(const f32x4*)(Vg + o0 + 4);
    };
    auto storeKp = [&](int p) {
        u16x8 r0;
#pragma unroll
        for (int i = 0; i < 4; ++i) {
            r0[i]     = f2bf(kA0[i] + tA0[i]);
            r0[i + 4] = f2bf(kA1[i] + tA1[i]);
        }
        *(u16x8*)&sKp[p][row0][cg] = r0;
    };
    auto storeVt = [&](int p) {
        const int kp = row0 ^ cg;
#pragma unroll
        for (int i = 0; i < 4; ++i) {
            sVt[p][cg + i][kp]     = f2bf(vA0[i]);
            sVt[p][cg + i + 4][kp] = f2bf(vA1[i]);
        }
    };

    f32x4 oacc[4];
#pragma unroll
    for (int dt = 0; dt < 4; ++dt)
#pragma unroll
        for (int j = 0; j < 4; ++j) oacc[dt][j] = 0.0f;

    loadKT(0);
    loadV(0);
    for (int kt = 0; kt < NKT; ++kt) {
        const int p = kt & 1;
        storeKp(p);
        storeVt(p);
        const int ktn = kt + 1 < NKT ? kt + 1 : 0;
        loadKT(ktn);
        loadV(ktn);
        barrier_lds();

        f32x4 acc[4];
#pragma unroll
        for (int ct = 0; ct < 4; ++ct)
#pragma unroll
            for (int j = 0; j < 4; ++j) acc[ct][j] = 0.0f;

        __builtin_amdgcn_s_setprio(1);
#pragma unroll
        for (int kk = 0; kk < 2; ++kk) {
            bf16x8 qa = kk ? qf1 : qf0;
#pragma unroll
            for (int ct = 0; ct < 4; ++ct) {
                BF8 bf; bf.u = *(const u16x8*)&sKp[p][ct * 16 + c][kk * 32 + g * 8];
                acc[ct] = __builtin_amdgcn_mfma_f32_16x16x32_bf16(bf.s, qa, acc[ct], 0, 0, 0);
            }
        }
        __builtin_amdgcn_s_setprio(0);

        const unsigned long long w = Mp[((long)b * TA_S + myq) * NKT + kt];
#pragma unroll
        for (int ct = 0; ct < 4; ++ct) {
            const unsigned nib = (unsigned)(w >> (ct * 16 + g * 4)) & 0xFu;
            float pv[4];
#pragma unroll
            for (int r = 0; r < 4; ++r) {
                float e = ((nib >> r) & 1u) ? __expf(acc[ct][r]) : 0.0f;
                pv[r] = e * invl;
            }
            u32x2 pk;
            pk[0] = (unsigned)f2bf(pv[0]) | ((unsigned)f2bf(pv[1]) << 16);
            pk[1] = (unsigned)f2bf(pv[2]) | ((unsigned)f2bf(pv[3]) << 16);
            *(u32x2*)&sP[wq0 + c][ct * 16 + g * 4] = pk;
        }

        BF8 pa0, pa1;
        pa0.u = *(const u16x8*)&sP[wq0 + c][g * 8];
        pa1.u = *(const u16x8*)&sP[wq0 + c][32 + g * 8];
        __builtin_amdgcn_s_setprio(1);
#pragma unroll
        for (int dt = 0; dt < 4; ++dt) {
            const int dRow = dt * 16 + c;
            const int kc0 = (g * 8) ^ (dRow & 56);
            const int kc1 = (32 + g * 8) ^ (dRow & 56);
            BF8 bv0, bv1;
            bv0.u = *(const u16x8*)&sVt[p][dRow][kc0];
            oacc[dt] = __builtin_amdgcn_mfma_f32_16x16x32_bf16(pa0.s, bv0.s, oacc[dt], 0, 0, 0);
            bv1.u = *(const u16x8*)&sVt[p][dRow][kc1];
            oacc[dt] = __builtin_amdgcn_mfma_f32_16x16x32_bf16(pa1.s, bv1.s, oacc[dt], 0, 0, 0);
        }
        __builtin_amdgcn_s_setprio(0);

        // P store: REGULAR cached stores (A/B vs nt). Each instruction covers two
        // full 128B lines (16 lanes x 16B contiguous) -> no RFO; L2 merges/drains.
#pragma unroll
        for (int j = 0; j < 4; ++j) {
            const int prow = 4 * j + g;
            u16x4 pv = *(const u16x4*)&sP[wq0 + prow][c * 4];
            f32x4 v;
#pragma unroll
            for (int i = 0; i < 4; ++i) v[i] = bf2f(pv[i]);
            *(f32x4*)(Pg + pBase + (long)(q0 + wq0 + prow) * TA_S + kt * KTILE + c * 4) = v;
        }
        // no trailing barrier: next tile writes buffer p^1
    }

#pragma unroll
    for (int dt = 0; dt < 4; ++dt) {
#pragma unroll
        for (int r = 0; r < 4; ++r) {
            __builtin_nontemporal_store(
                oacc[dt][r],
                &Og[xBase + (long)(q0 + wq0 + g * 4 + r) * TA_D + dt * 16 + c]);
        }
    }
}

// ---- Monolithic fallback (r11), unpacked mask, used only if ws too small ----
__global__ __launch_bounds__(BLOCK, 4) void ta_mono(
    const float* __restrict__ Qg,
    const float* __restrict__ Kg,
    const float* __restrict__ Vg,
    const float* __restrict__ Tg,
    const int* __restrict__ Mg,
    float* __restrict__ Og,
    float* __restrict__ Pg)
{
    __shared__ unsigned short sKp[2][KTILE][72];
    __shared__ unsigned short sVt[2][TA_D][72];
    __shared__ unsigned short sP[QB][72];

    const int tid  = threadIdx.x;
    const int wave = tid >> 6;
    const int lane = tid & 63;
    const int c    = lane & 15;
    const int g    = lane >> 4;
    const int row0 = tid >> 3;
    const int cg   = (tid & 7) * 8;

    const int did = blockIdx.x + 16 * (blockIdx.y + 16 * blockIdx.z);
    const int wid = (did & 7) * 64 + (did >> 3);
    const int q0  = (wid & 15) * QB;
    const int h   = (wid >> 4) & 15;
    const int b   = wid >> 8;

    const long bh    = (long)b * TA_H + h;
    const long xBase = bh * (long)TA_S * TA_D;
    const long pBase = bh * (long)TA_S * TA_S;
    const long mBase = (long)b * (long)TA_S * TA_S;
    const int  wq0   = wave * 16;
    const int  myq   = q0 + wq0 + c;

    bf16x8 qf0, qf1;
    {
        const float* qp = Qg + xBase + (long)myq * TA_D + g * 8;
        f32x4 a0 = *(const f32x4*)(qp);
        f32x4 a1 = *(const f32x4*)(qp + 4);
        f32x4 b0 = *(const f32x4*)(qp + 32);
        f32x4 b1 = *(const f32x4*)(qp + 36);
        BF8 u0, u1;
#pragma unroll
        for (int i = 0; i < 4; ++i) {
            u0.u[i]     = f2bf(a0[i] * 0.125f);
            u0.u[i + 4] = f2bf(a1[i] * 0.125f);
            u1.u[i]     = f2bf(b0[i] * 0.125f);
            u1.u[i + 4] = f2bf(b1[i] * 0.125f);
        }
        qf0 = u0.s; qf1 = u1.s;
    }

    f32x4 kA0, kA1, tA0, tA1, vA0, vA1;
    auto loadKT = [&](int kt) {
        const long o0 = xBase + (long)(kt * KTILE + row0) * TA_D + cg;
        kA0 = *(const f32x4*)(Kg + o0); kA1 = *(const f32x4*)(Kg + o0 + 4);
        tA0 = *(const f32x4*)(Tg + o0); tA1 = *(const f32x4*)(Tg + o0 + 4);
    };
    auto loadV = [&](int kt) {
        const long o0 = xBase + (long)(kt * KTILE + row0) * TA_D + cg;
        vA0 = *(const f32x4*)(Vg + o0); vA1 = *(const f32x4*)(Vg + o0 + 4);
    };
    auto storeKp = [&](int p) {
        u16x8 r0;
#pragma unroll
        for (int i = 0; i < 4; ++i) {
            r0[i]     = f2bf(kA0[i] + tA0[i]);
            r0[i + 4] = f2bf(kA1[i] + tA1[i]);
        }
        *(u16x8*)&sKp[p][row0][cg] = r0;
    };
    auto storeVt = [&](int p) {
        const int kp = row0 ^ cg;
#pragma unroll
        for (int i = 0; i < 4; ++i) {
            sVt[p][cg + i][kp]     = f2bf(vA0[i]);
            sVt[p][cg + i + 4][kp] = f2bf(vA1[i]);
        }
    };
    auto maskWord = [&](int kt) -> unsigned long long {
        const int* mp = Mg + mBase + (long)myq * TA_S + kt * KTILE;
        unsigned long long w = 0;
#pragma unroll
        for (int ct = 0; ct < 4; ++ct)
#pragma unroll
            for (int r = 0; r < 4; ++r)
                w |= mp[ct * 16 + g * 4 + r] ? (1ull << (ct * 16 + g * 4 + r)) : 0ull;
        return w;
    };

    float lpart = 0.0f;
    loadKT(0);
    for (int kt = 0; kt < NKT; ++kt) {
        const int p = kt & 1;
        storeKp(p);
        loadKT(kt + 1 < NKT ? kt + 1 : 0);
        barrier_lds();

        f32x4 acc[4];
#pragma unroll
        for (int ct = 0; ct < 4; ++ct)
#pragma unroll
            for (int j = 0; j < 4; ++j) acc[ct][j] = 0.0f;

#pragma unroll
        for (int kk = 0; kk < 2; ++kk) {
            bf16x8 qa = kk ? qf1 : qf0;
#pragma unroll
            for (int ct = 0; ct < 4; ++ct) {
                BF8 bf; bf.u = *(const u16x8*)&sKp[p][ct * 16 + c][kk * 32 + g * 8];
                acc[ct] = __builtin_amdgcn_mfma_f32_16x16x32_bf16(bf.s, qa, acc[ct], 0, 0, 0);
            }
        }

        const unsigned long long w = maskWord(kt);
#pragma unroll
        for (int ct = 0; ct < 4; ++ct) {
            const unsigned nib = (unsigned)(w >> (ct * 16 + g * 4)) & 0xFu;
#pragma unroll
            for (int r = 0; r < 4; ++r)
                lpart += ((nib >> r) & 1u) ? __expf(acc[ct][r]) : 0.0f;
        }
    }

    loadV(0);
    float l = lpart;
    l += __shfl_xor(l, 16);
    l += __shfl_xor(l, 32);
    const float invl = (l > 0.0f) ? (1.0f / l) : 0.0f;

    f32x4 oacc[4];
#pragma unroll
    for (int dt = 0; dt < 4; ++dt)
#pragma unroll
        for (int j = 0; j < 4; ++j) oacc[dt][j] = 0.0f;

    for (int kt = 0; kt < NKT; ++kt) {
        const int p = kt & 1;
        storeKp(p);
        storeVt(p);
        const int ktn = kt + 1 < NKT ? kt + 1 : 0;
        loadKT(ktn);
        loadV(ktn);
        barrier_lds();

        f32x4 acc[4];
#pragma unroll
        for (int ct = 0; ct < 4; ++ct)
#pragma unroll
            for (int j = 0; j < 4; ++j) acc[ct][j] = 0.0f;

#pragma unroll
        for (int kk = 0; kk < 2; ++kk) {
            bf16x8 qa = kk ? qf1 : qf0;
#pragma unroll
            for (int ct = 0; ct < 4; ++ct) {
                BF8 bf; bf.u = *(const u16x8*)&sKp[p][ct * 16 + c][kk * 32 + g * 8];
                acc[ct] = __builtin_amdgcn_mfma_f32_16x16x32_bf16(bf.s, qa, acc[ct], 0, 0, 0);
            }
        }

        const unsigned long long w = maskWord(kt);
#pragma unroll
        for (int ct = 0; ct < 4; ++ct) {
            const unsigned nib = (unsigned)(w >> (ct * 16 + g * 4)) & 0xFu;
            float pv[4];
#pragma unroll
            for (int r = 0; r < 4; ++r) {
                float e = ((nib >> r) & 1u) ? __expf(acc[ct][r]) : 0.0f;
                pv[r] = e * invl;
            }
            u32x2 pk;
            pk[0] = (unsigned)f2bf(pv[0]) | ((unsigned)f2bf(pv[1]) << 16);
            pk[1] = (unsigned)f2bf(pv[2]) | ((unsigned)f2bf(pv[3]) << 16);
            *(u32x2*)&sP[wq0 + c][ct * 16 + g * 4] = pk;
        }

        BF8 pa0, pa1;
        pa0.u = *(const u16x8*)&sP[wq0 + c][g * 8];
        pa1.u = *(const u16x8*)&sP[wq0 + c][32 + g * 8];
#pragma unroll
        for (int dt = 0; dt < 4; ++dt) {
            const int dRow = dt * 16 + c;
            const int kc0 = (g * 8) ^ (dRow & 56);
            const int kc1 = (32 + g * 8) ^ (dRow & 56);
            BF8 bv0, bv1;
            bv0.u = *(const u16x8*)&sVt[p][dRow][kc0];
            oacc[dt] = __builtin_amdgcn_mfma_f32_16x16x32_bf16(pa0.s, bv0.s, oacc[dt], 0, 0, 0);
            bv1.u = *(const u16x8*)&sVt[p][dRow][kc1];
            oacc[dt] = __builtin_amdgcn_mfma_f32_16x16x32_bf16(pa1.s, bv1.s, oacc[dt], 0, 0, 0);
        }

#pragma unroll
        for (int j = 0; j < 4; ++j) {
            const int prow = 4 * j + g;
            u16x4 pv = *(const u16x4*)&sP[wq0 + prow][c * 4];
            f32x4 v;
#pragma unroll
            for (int i = 0; i < 4; ++i) v[i] = bf2f(pv[i]);
            *(f32x4*)(Pg + pBase + (long)(q0 + wq0 + prow) * TA_S + kt * KTILE + c * 4) = v;
        }
    }

#pragma unroll
    for (int dt = 0; dt < 4; ++dt) {
#pragma unroll
        for (int r = 0; r < 4; ++r) {
            __builtin_nontemporal_store(
                oacc[dt][r],
                &Og[xBase + (long)(q0 + wq0 + g * 4 + r) * TA_D + dt * 16 + c]);
        }
    }
}

extern "C" void kernel_launch(void* const* d_in, const int* in_sizes, int n_in,
                              void* d_out, int out_size, void* d_ws, size_t ws_size,
                              hipStream_t stream) {
    const float* Q = (const float*)d_in[0];
    const float* K = (const float*)d_in[1];
    const float* V = (const float*)d_in[2];
    const float* T = (const float*)d_in[3];
    const int*   M = (const int*)d_in[4];

    float* O = (float*)d_out;
    float* P = O + (long)TA_B * TA_H * TA_S * TA_D;

    const size_t maskWs = (size_t)TA_B * TA_S * NKT * 8;              // 1 MB
    const size_t lWs    = (size_t)TA_B * TA_H * TA_S * NSPLIT * 4;    // 1 MB

    unsigned long long* Mp = (unsigned long long*)d_ws;
    float* wsL = (float*)((char*)d_ws + maskWs);

    dim3 block(BLOCK);

    if (ws_size >= maskWs + lWs) {
        hipLaunchKernelGGL(pack_mask, dim3(512), dim3(256), 0, stream, M, Mp);
        hipLaunchKernelGGL(ta_passA, dim3(64, 16, 2), block, 0, stream, Q, K, T, Mp, wsL);
        hipLaunchKernelGGL(ta_passB, dim3(16, 16, 2), block, 0, stream, Q, K, V, T, Mp, wsL, O, P);
    } else {
        hipLaunchKernelGGL(ta_mono, dim3(16, 16, 2), block, 0, stream, Q, K, V, T, M, O, P);
    }
}

// Round 15
// 193.005 us; speedup vs baseline: 1.5449x; 1.5449x over previous
//
#include <hip/hip_runtime.h>
#include <hip/hip_bf16.h>

#define TA_B 2
#define TA_H 16
#define TA_S 2048
#define TA_D 64
#define KTILE 64
#define QB 128
#define BLOCK 512
#define NKT (TA_S / KTILE)
#define NSPLIT 4
#define KT_PER (NKT / NSPLIT)

typedef __attribute__((ext_vector_type(4))) float f32x4;
typedef __attribute__((ext_vector_type(8))) short bf16x8;
typedef __attribute__((ext_vector_type(8))) unsigned short u16x8;
typedef __attribute__((ext_vector_type(4))) unsigned short u16x4;
typedef __attribute__((ext_vector_type(2))) unsigned int u32x2;

union BF8 { u16x8 u; bf16x8 s; };

__device__ __forceinline__ unsigned short f2bf(float f) {
    union { float f; unsigned int i; } v; v.f = f;
    unsigned int x = v.i;
    unsigned int r = x + 0x7FFFu + ((x >> 16) & 1u);
    return (unsigned short)(r >> 16);
}
__device__ __forceinline__ float bf2f(unsigned short u) {
    union { unsigned int i; float f; } v; v.i = ((unsigned int)u) << 16; return v.f;
}

__device__ __forceinline__ void barrier_lds() {
    asm volatile("s_waitcnt lgkmcnt(0)" ::: "memory");
    __builtin_amdgcn_sched_barrier(0);
    __builtin_amdgcn_s_barrier();
    __builtin_amdgcn_sched_barrier(0);
}

// ---- mask bit-pack: 33.6 MB int32 -> 1 MB bits, via wave ballot ----
__global__ __launch_bounds__(256) void pack_mask(const int* __restrict__ M,
                                                 unsigned long long* __restrict__ Mp) {
    const int nw = TA_B * TA_S * NKT;
    const int wavesTotal = (gridDim.x * blockDim.x) >> 6;
    const int wid  = (blockIdx.x * blockDim.x + threadIdx.x) >> 6;
    const int lane = threadIdx.x & 63;
    for (int w = wid; w < nw; w += wavesTotal) {
        int mv = M[(long)w * 64 + lane];
        unsigned long long bits = __ballot(mv != 0);
        if (lane == 0) Mp[w] = bits;
    }
}

// ---- Pass A, split-K: partial l over KT_PER tiles -> wsL[q][split] ----
__global__ __launch_bounds__(BLOCK, 4) void ta_passA(
    const float* __restrict__ Qg,
    const float* __restrict__ Kg,
    const float* __restrict__ Tg,
    const unsigned long long* __restrict__ Mp,
    float* __restrict__ wsL)
{
    __shared__ unsigned short sKp[2][KTILE][72];   // dbuf bf16(K+T)

    const int tid  = threadIdx.x;
    const int wave = tid >> 6;
    const int lane = tid & 63;
    const int c    = lane & 15;
    const int g    = lane >> 4;
    const int row0 = tid >> 3;
    const int cg   = (tid & 7) * 8;

    // Bijective XCD swizzle over 2048 blocks; consecutive wid share (b,h,split).
    const int did = blockIdx.x + 64 * (blockIdx.y + 16 * blockIdx.z);
    const int wid = (did & 7) * 256 + (did >> 3);
    const int q0    = (wid & 15) * QB;
    const int split = (wid >> 4) & 3;
    const int h     = (wid >> 6) & 15;
    const int b     = wid >> 10;

    const long bh    = (long)b * TA_H + h;
    const long xBase = bh * (long)TA_S * TA_D;
    const int  wq0   = wave * 16;
    const int  myq   = q0 + wq0 + c;
    const int  kt0   = split * KT_PER;

    bf16x8 qf0, qf1;
    {
        const float* qp = Qg + xBase + (long)myq * TA_D + g * 8;
        f32x4 a0 = *(const f32x4*)(qp);
        f32x4 a1 = *(const f32x4*)(qp + 4);
        f32x4 b0 = *(const f32x4*)(qp + 32);
        f32x4 b1 = *(const f32x4*)(qp + 36);
        BF8 u0, u1;
#pragma unroll
        for (int i = 0; i < 4; ++i) {
            u0.u[i]     = f2bf(a0[i] * 0.125f);
            u0.u[i + 4] = f2bf(a1[i] * 0.125f);
            u1.u[i]     = f2bf(b0[i] * 0.125f);
            u1.u[i + 4] = f2bf(b1[i] * 0.125f);
        }
        qf0 = u0.s; qf1 = u1.s;
    }

    f32x4 kA0, kA1, tA0, tA1;
    auto loadKT = [&](int kt) {
        const long o0 = xBase + (long)(kt * KTILE + row0) * TA_D + cg;
        kA0 = *(const f32x4*)(Kg + o0); kA1 = *(const f32x4*)(Kg + o0 + 4);
        tA0 = *(const f32x4*)(Tg + o0); tA1 = *(const f32x4*)(Tg + o0 + 4);
    };
    auto storeKp = [&](int p) {
        u16x8 r0;
#pragma unroll
        for (int i = 0; i < 4; ++i) {
            r0[i]     = f2bf(kA0[i] + tA0[i]);
            r0[i + 4] = f2bf(kA1[i] + tA1[i]);
        }
        *(u16x8*)&sKp[p][row0][cg] = r0;
    };

    float lpart = 0.0f;
    loadKT(kt0);
    for (int i = 0; i < KT_PER; ++i) {
        const int kt = kt0 + i;
        const int p  = i & 1;
        storeKp(p);
        loadKT(i + 1 < KT_PER ? kt + 1 : kt0);
        barrier_lds();

        f32x4 acc[4];
#pragma unroll
        for (int ct = 0; ct < 4; ++ct)
#pragma unroll
            for (int j = 0; j < 4; ++j) acc[ct][j] = 0.0f;

        __builtin_amdgcn_s_setprio(1);
#pragma unroll
        for (int kk = 0; kk < 2; ++kk) {
            bf16x8 qa = kk ? qf1 : qf0;
#pragma unroll
            for (int ct = 0; ct < 4; ++ct) {
                BF8 bf; bf.u = *(const u16x8*)&sKp[p][ct * 16 + c][kk * 32 + g * 8];
                acc[ct] = __builtin_amdgcn_mfma_f32_16x16x32_bf16(bf.s, qa, acc[ct], 0, 0, 0);
            }
        }
        __builtin_amdgcn_s_setprio(0);

        const unsigned long long w = Mp[((long)b * TA_S + myq) * NKT + kt];
#pragma unroll
        for (int ct = 0; ct < 4; ++ct) {
            const unsigned nib = (unsigned)(w >> (ct * 16 + g * 4)) & 0xFu;
#pragma unroll
            for (int r = 0; r < 4; ++r)
                lpart += ((nib >> r) & 1u) ? __expf(acc[ct][r]) : 0.0f;
        }
        // no trailing barrier: next tile writes buffer p^1
    }

    float l = lpart;
    l += __shfl_xor(l, 16);
    l += __shfl_xor(l, 32);
    if (g == 0)
        wsL[((long)bh * TA_S + myq) * NSPLIT + split] = l;
}

// ---- Pass B: reads summed l, recomputes S^T, writes normalized P + O ----
__global__ __launch_bounds__(BLOCK, 4) void ta_passB(
    const float* __restrict__ Qg,
    const float* __restrict__ Kg,
    const float* __restrict__ Vg,
    const float* __restrict__ Tg,
    const unsigned long long* __restrict__ Mp,
    const float* __restrict__ wsL,
    float* __restrict__ Og,
    float* __restrict__ Pg)
{
    __shared__ unsigned short sKp[2][KTILE][72];
    __shared__ unsigned short sVt[2][TA_D][72];
    __shared__ unsigned short sP[QB][72];

    const int tid  = threadIdx.x;
    const int wave = tid >> 6;
    const int lane = tid & 63;
    const int c    = lane & 15;
    const int g    = lane >> 4;
    const int row0 = tid >> 3;
    const int cg   = (tid & 7) * 8;

    const int did = blockIdx.x + 16 * (blockIdx.y + 16 * blockIdx.z);
    const int wid = (did & 7) * 64 + (did >> 3);
    const int q0  = (wid & 15) * QB;
    const int h   = (wid >> 4) & 15;
    const int b   = wid >> 8;

    const long bh    = (long)b * TA_H + h;
    const long xBase = bh * (long)TA_S * TA_D;
    const long pBase = bh * (long)TA_S * TA_S;
    const int  wq0   = wave * 16;
    const int  myq   = q0 + wq0 + c;

    bf16x8 qf0, qf1;
    {
        const float* qp = Qg + xBase + (long)myq * TA_D + g * 8;
        f32x4 a0 = *(const f32x4*)(qp);
        f32x4 a1 = *(const f32x4*)(qp + 4);
        f32x4 b0 = *(const f32x4*)(qp + 32);
        f32x4 b1 = *(const f32x4*)(qp + 36);
        BF8 u0, u1;
#pragma unroll
        for (int i = 0; i < 4; ++i) {
            u0.u[i]     = f2bf(a0[i] * 0.125f);
            u0.u[i + 4] = f2bf(a1[i] * 0.125f);
            u1.u[i]     = f2bf(b0[i] * 0.125f);
            u1.u[i + 4] = f2bf(b1[i] * 0.125f);
        }
        qf0 = u0.s; qf1 = u1.s;
    }

    // l = sum of 4 split partials (one f32x4 load per lane)
    float invl;
    {
        f32x4 lp = *(const f32x4*)&wsL[((long)bh * TA_S + myq) * NSPLIT];
        float l = lp[0] + lp[1] + lp[2] + lp[3];
        invl = (l > 0.0f) ? (1.0f / l) : 0.0f;
    }

    f32x4 kA0, kA1, tA0, tA1, vA0, vA1;
    auto loadKT = [&](int kt) {
        const long o0 = xBase + (long)(kt * KTILE + row0) * TA_D + cg;
        kA0 = *(const f32x4*)(Kg + o0); kA1 = *(const f32x4*)(Kg + o0 + 4);
        tA0 = *(const f32x4*)(Tg + o0); tA1 = *(const f32x4*)(Tg + o0 + 4);
    };
    auto loadV = [&](int kt) {
        const long o0 = xBase + (long)(kt * KTILE + row0) * TA_D + cg;
        vA0 = *(const f32x4*)(Vg + o0); vA1 = *(const f32x4*)(Vg + o0 + 4);
    };
    auto storeKp = [&](int p) {
        u16x8 r0;
#pragma unroll
        for (int i = 0; i < 4; ++i) {
            r0[i]     = f2bf(kA0[i] + tA0[i]);
            r0[i + 4] = f2bf(kA1[i] + tA1[i]);
        }
        *(u16x8*)&sKp[p][row0][cg] = r0;
    };
    auto storeVt = [&](int p) {
        const int kp = row0 ^ cg;
#pragma unroll
        for (int i = 0; i < 4; ++i) {
            sVt[p][cg + i][kp]     = f2bf(vA0[i]);
            sVt[p][cg + i + 4][kp] = f2bf(vA1[i]);
        }
    };

    f32x4 oacc[4];
#pragma unroll
    for (int dt = 0; dt < 4; ++dt)
#pragma unroll
        for (int j = 0; j < 4; ++j) oacc[dt][j] = 0.0f;

    loadKT(0);
    loadV(0);
    for (int kt = 0; kt < NKT; ++kt) {
        const int p = kt & 1;
        storeKp(p);
        storeVt(p);
        const int ktn = kt + 1 < NKT ? kt + 1 : 0;
        loadKT(ktn);
        loadV(ktn);
        barrier_lds();

        f32x4 acc[4];
#pragma unroll
        for (int ct = 0; ct < 4; ++ct)
#pragma unroll
            for (int j = 0; j < 4; ++j) acc[ct][j] = 0.0f;

        __builtin_amdgcn_s_setprio(1);
#pragma unroll
        for (int kk = 0; kk < 2; ++kk) {
            bf16x8 qa = kk ? qf1 : qf0;
#pragma unroll
            for (int ct = 0; ct < 4; ++ct) {
                BF8 bf; bf.u = *(const u16x8*)&sKp[p][ct * 16 + c][kk * 32 + g * 8];
                acc[ct] = __builtin_amdgcn_mfma_f32_16x16x32_bf16(bf.s, qa, acc[ct], 0, 0, 0);
            }
        }
        __builtin_amdgcn_s_setprio(0);

        const unsigned long long w = Mp[((long)b * TA_S + myq) * NKT + kt];
#pragma unroll
        for (int ct = 0; ct < 4; ++ct) {
            const unsigned nib = (unsigned)(w >> (ct * 16 + g * 4)) & 0xFu;
            float pv[4];
#pragma unroll
            for (int r = 0; r < 4; ++r) {
                float e = ((nib >> r) & 1u) ? __expf(acc[ct][r]) : 0.0f;
                pv[r] = e * invl;
            }
            u32x2 pk;
            pk[0] = (unsigned)f2bf(pv[0]) | ((unsigned)f2bf(pv[1]) << 16);
            pk[1] = (unsigned)f2bf(pv[2]) | ((unsigned)f2bf(pv[3]) << 16);
            *(u32x2*)&sP[wq0 + c][ct * 16 + g * 4] = pk;
        }

        BF8 pa0, pa1;
        pa0.u = *(const u16x8*)&sP[wq0 + c][g * 8];
        pa1.u = *(const u16x8*)&sP[wq0 + c][32 + g * 8];
        __builtin_amdgcn_s_setprio(1);
#pragma unroll
        for (int dt = 0; dt < 4; ++dt) {
            const int dRow = dt * 16 + c;
            const int kc0 = (g * 8) ^ (dRow & 56);
            const int kc1 = (32 + g * 8) ^ (dRow & 56);
            BF8 bv0, bv1;
            bv0.u = *(const u16x8*)&sVt[p][dRow][kc0];
            oacc[dt] = __builtin_amdgcn_mfma_f32_16x16x32_bf16(pa0.s, bv0.s, oacc[dt], 0, 0, 0);
            bv1.u = *(const u16x8*)&sVt[p][dRow][kc1];
            oacc[dt] = __builtin_amdgcn_mfma_f32_16x16x32_bf16(pa1.s, bv1.s, oacc[dt], 0, 0, 0);
        }
        __builtin_amdgcn_s_setprio(0);

        // P store: nt, full 256B row-spans per instruction (A/B r14 proved nt >> cached).
#pragma unroll
        for (int j = 0; j < 4; ++j) {
            const int prow = 4 * j + g;
            u16x4 pv = *(const u16x4*)&sP[wq0 + prow][c * 4];
            f32x4 v;
#pragma unroll
            for (int i = 0; i < 4; ++i) v[i] = bf2f(pv[i]);
            __builtin_nontemporal_store(
                v, (f32x4*)(Pg + pBase + (long)(q0 + wq0 + prow) * TA_S + kt * KTILE + c * 4));
        }
        // no trailing barrier: next tile writes buffer p^1
    }

#pragma unroll
    for (int dt = 0; dt < 4; ++dt) {
#pragma unroll
        for (int r = 0; r < 4; ++r) {
            __builtin_nontemporal_store(
                oacc[dt][r],
                &Og[xBase + (long)(q0 + wq0 + g * 4 + r) * TA_D + dt * 16 + c]);
        }
    }
}

// ---- Monolithic fallback (r11), unpacked mask, used only if ws too small ----
__global__ __launch_bounds__(BLOCK, 4) void ta_mono(
    const float* __restrict__ Qg,
    const float* __restrict__ Kg,
    const float* __restrict__ Vg,
    const float* __restrict__ Tg,
    const int* __restrict__ Mg,
    float* __restrict__ Og,
    float* __restrict__ Pg)
{
    __shared__ unsigned short sKp[2][KTILE][72];
    __shared__ unsigned short sVt[2][TA_D][72];
    __shared__ unsigned short sP[QB][72];

    const int tid  = threadIdx.x;
    const int wave = tid >> 6;
    const int lane = tid & 63;
    const int c    = lane & 15;
    const int g    = lane >> 4;
    const int row0 = tid >> 3;
    const int cg   = (tid & 7) * 8;

    const int did = blockIdx.x + 16 * (blockIdx.y + 16 * blockIdx.z);
    const int wid = (did & 7) * 64 + (did >> 3);
    const int q0  = (wid & 15) * QB;
    const int h   = (wid >> 4) & 15;
    const int b   = wid >> 8;

    const long bh    = (long)b * TA_H + h;
    const long xBase = bh * (long)TA_S * TA_D;
    const long pBase = bh * (long)TA_S * TA_S;
    const long mBase = (long)b * (long)TA_S * TA_S;
    const int  wq0   = wave * 16;
    const int  myq   = q0 + wq0 + c;

    bf16x8 qf0, qf1;
    {
        const float* qp = Qg + xBase + (long)myq * TA_D + g * 8;
        f32x4 a0 = *(const f32x4*)(qp);
        f32x4 a1 = *(const f32x4*)(qp + 4);
        f32x4 b0 = *(const f32x4*)(qp + 32);
        f32x4 b1 = *(const f32x4*)(qp + 36);
        BF8 u0, u1;
#pragma unroll
        for (int i = 0; i < 4; ++i) {
            u0.u[i]     = f2bf(a0[i] * 0.125f);
            u0.u[i + 4] = f2bf(a1[i] * 0.125f);
            u1.u[i]     = f2bf(b0[i] * 0.125f);
            u1.u[i + 4] = f2bf(b1[i] * 0.125f);
        }
        qf0 = u0.s; qf1 = u1.s;
    }

    f32x4 kA0, kA1, tA0, tA1, vA0, vA1;
    auto loadKT = [&](int kt) {
        const long o0 = xBase + (long)(kt * KTILE + row0) * TA_D + cg;
        kA0 = *(const f32x4*)(Kg + o0); kA1 = *(const f32x4*)(Kg + o0 + 4);
        tA0 = *(const f32x4*)(Tg + o0); tA1 = *(const f32x4*)(Tg + o0 + 4);
    };
    auto loadV = [&](int kt) {
        const long o0 = xBase + (long)(kt * KTILE + row0) * TA_D + cg;
        vA0 = *(const f32x4*)(Vg + o0); vA1 = *(const f32x4*)(Vg + o0 + 4);
    };
    auto storeKp = [&](int p) {
        u16x8 r0;
#pragma unroll
        for (int i = 0; i < 4; ++i) {
            r0[i]     = f2bf(kA0[i] + tA0[i]);
            r0[i + 4] = f2bf(kA1[i] + tA1[i]);
        }
        *(u16x8*)&sKp[p][row0][cg] = r0;
    };
    auto storeVt = [&](int p) {
        const int kp = row0 ^ cg;
#pragma unroll
        for (int i = 0; i < 4; ++i) {
            sVt[p][cg + i][kp]     = f2bf(vA0[i]);
            sVt[p][cg + i + 4][kp] = f2bf(vA1[i]);
        }
    };
    auto maskWord = [&](int kt) -> unsigned long long {
        const int* mp = Mg + mBase + (long)myq * TA_S + kt * KTILE;
        unsigned long long w = 0;
#pragma unroll
        for (int ct = 0; ct < 4; ++ct)
#pragma unroll
            for (int r = 0; r < 4; ++r)
                w |= mp[ct * 16 + g * 4 + r] ? (1ull << (ct * 16 + g * 4 + r)) : 0ull;
        return w;
    };

    float lpart = 0.0f;
    loadKT(0);
    for (int kt = 0; kt < NKT; ++kt) {
        const int p = kt & 1;
        storeKp(p);
        loadKT(kt + 1 < NKT ? kt + 1 : 0);
        barrier_lds();

        f32x4 acc[4];
#pragma unroll
        for (int ct = 0; ct < 4; ++ct)
#pragma unroll
            for (int j = 0; j < 4; ++j) acc[ct][j] = 0.0f;

#pragma unroll
        for (int kk = 0; kk < 2; ++kk) {
            bf16x8 qa = kk ? qf1 : qf0;
#pragma unroll
            for (int ct = 0; ct < 4; ++ct) {
                BF8 bf; bf.u = *(const u16x8*)&sKp[p][ct * 16 + c][kk * 32 + g * 8];
                acc[ct] = __builtin_amdgcn_mfma_f32_16x16x32_bf16(bf.s, qa, acc[ct], 0, 0, 0);
            }
        }

        const unsigned long long w = maskWord(kt);
#pragma unroll
        for (int ct = 0; ct < 4; ++ct) {
            const unsigned nib = (unsigned)(w >> (ct * 16 + g * 4)) & 0xFu;
#pragma unroll
            for (int r = 0; r < 4; ++r)
                lpart += ((nib >> r) & 1u) ? __expf(acc[ct][r]) : 0.0f;
        }
    }

    loadV(0);
    float l = lpart;
    l += __shfl_xor(l, 16);
    l += __shfl_xor(l, 32);
    const float invl = (l > 0.0f) ? (1.0f / l) : 0.0f;

    f32x4 oacc[4];
#pragma unroll
    for (int dt = 0; dt < 4; ++dt)
#pragma unroll
        for (int j = 0; j < 4; ++j) oacc[dt][j] = 0.0f;

    for (int kt = 0; kt < NKT; ++kt) {
        const int p = kt & 1;
        storeKp(p);
        storeVt(p);
        const int ktn = kt + 1 < NKT ? kt + 1 : 0;
        loadKT(ktn);
        loadV(ktn);
        barrier_lds();

        f32x4 acc[4];
#pragma unroll
        for (int ct = 0; ct < 4; ++ct)
#pragma unroll
            for (int j = 0; j < 4; ++j) acc[ct][j] = 0.0f;

#pragma unroll
        for (int kk = 0; kk < 2; ++kk) {
            bf16x8 qa = kk ? qf1 : qf0;
#pragma unroll
            for (int ct = 0; ct < 4; ++ct) {
                BF8 bf; bf.u = *(const u16x8*)&sKp[p][ct * 16 + c][kk * 32 + g * 8];
                acc[ct] = __builtin_amdgcn_mfma_f32_16x16x32_bf16(bf.s, qa, acc[ct], 0, 0, 0);
            }
        }

        const unsigned long long w = maskWord(kt);
#pragma unroll
        for (int ct = 0; ct < 4; ++ct) {
            const unsigned nib = (unsigned)(w >> (ct * 16 + g * 4)) & 0xFu;
            float pv[4];
#pragma unroll
            for (int r = 0; r < 4; ++r) {
                float e = ((nib >> r) & 1u) ? __expf(acc[ct][r]) : 0.0f;
                pv[r] = e * invl;
            }
            u32x2 pk;
            pk[0] = (unsigned)f2bf(pv[0]) | ((unsigned)f2bf(pv[1]) << 16);
            pk[1] = (unsigned)f2bf(pv[2]) | ((unsigned)f2bf(pv[3]) << 16);
            *(u32x2*)&sP[wq0 + c][ct * 16 + g * 4] = pk;
        }

        BF8 pa0, pa1;
        pa0.u = *(const u16x8*)&sP[wq0 + c][g * 8];
        pa1.u = *(const u16x8*)&sP[wq0 + c][32 + g * 8];
#pragma unroll
        for (int dt = 0; dt < 4; ++dt) {
            const int dRow = dt * 16 + c;
            const int kc0 = (g * 8) ^ (dRow & 56);
            const int kc1 = (32 + g * 8) ^ (dRow & 56);
            BF8 bv0, bv1;
            bv0.u = *(const u16x8*)&sVt[p][dRow][kc0];
            oacc[dt] = __builtin_amdgcn_mfma_f32_16x16x32_bf16(pa0.s, bv0.s, oacc[dt], 0, 0, 0);
            bv1.u = *(const u16x8*)&sVt[p][dRow][kc1];
            oacc[dt] = __builtin_amdgcn_mfma_f32_16x16x32_bf16(pa1.s, bv1.s, oacc[dt], 0, 0, 0);
        }

#pragma unroll
        for (int j = 0; j < 4; ++j) {
            const int prow = 4 * j + g;
            u16x4 pv = *(const u16x4*)&sP[wq0 + prow][c * 4];
            f32x4 v;
#pragma unroll
            for (int i = 0; i < 4; ++i) v[i] = bf2f(pv[i]);
            __builtin_nontemporal_store(
                v, (f32x4*)(Pg + pBase + (long)(q0 + wq0 + prow) * TA_S + kt * KTILE + c * 4));
        }
    }

#pragma unroll
    for (int dt = 0; dt < 4; ++dt) {
#pragma unroll
        for (int r = 0; r < 4; ++r) {
            __builtin_nontemporal_store(
                oacc[dt][r],
                &Og[xBase + (long)(q0 + wq0 + g * 4 + r) * TA_D + dt * 16 + c]);
        }
    }
}

extern "C" void kernel_launch(void* const* d_in, const int* in_sizes, int n_in,
                              void* d_out, int out_size, void* d_ws, size_t ws_size,
                              hipStream_t stream) {
    const float* Q = (const float*)d_in[0];
    const float* K = (const float*)d_in[1];
    const float* V = (const float*)d_in[2];
    const float* T = (const float*)d_in[3];
    const int*   M = (const int*)d_in[4];

    float* O = (float*)d_out;
    float* P = O + (long)TA_B * TA_H * TA_S * TA_D;

    const size_t maskWs = (size_t)TA_B * TA_S * NKT * 8;              // 1 MB
    const size_t lWs    = (size_t)TA_B * TA_H * TA_S * NSPLIT * 4;    // 1 MB

    unsigned long long* Mp = (unsigned long long*)d_ws;
    float* wsL = (float*)((char*)d_ws + maskWs);

    dim3 block(BLOCK);

    if (ws_size >= maskWs + lWs) {
        hipLaunchKernelGGL(pack_mask, dim3(512), dim3(256), 0, stream, M, Mp);
        hipLaunchKernelGGL(ta_passA, dim3(64, 16, 2), block, 0, stream, Q, K, T, Mp, wsL);
        hipLaunchKernelGGL(ta_passB, dim3(16, 16, 2), block, 0, stream, Q, K, V, T, Mp, wsL, O, P);
    } else {
        hipLaunchKernelGGL(ta_mono, dim3(16, 16, 2), block, 0, stream, Q, K, V, T, M, O, P);
    }
}